// Round 1
// baseline (381.592 us; speedup 1.0000x reference)
//
#include <hip/hip_runtime.h>
#include <hip/hip_bf16.h>
#include <cstdint>
#include <cstddef>

using bf16x8 = __attribute__((ext_vector_type(8))) short;
using f32x4  = __attribute__((ext_vector_type(4))) float;

#define GAS __attribute__((address_space(1)))
#define LAS __attribute__((address_space(3)))

static constexpr int Tdim = 4096;
static constexpr int Ddim = 2048;
static constexpr int N1   = 6144;   // 3*Ddim

__device__ __forceinline__ unsigned short f32_to_bf16(float f) {
    union { float f; unsigned u; } v; v.f = f;
    return (unsigned short)((v.u + 0x7FFFu + ((v.u >> 16) & 1u)) >> 16);
}
__device__ __forceinline__ float bflo(unsigned u){ union{unsigned x;float f;}v; v.x = u << 16;        return v.f; }
__device__ __forceinline__ float bfhi(unsigned u){ union{unsigned x;float f;}v; v.x = u & 0xFFFF0000u; return v.f; }

// ---------------- convert f32 -> bf16 (vectorized, grid-stride) ----------------
__global__ __launch_bounds__(256) void cvt_bf16(const float* __restrict__ src,
                                                unsigned short* __restrict__ dst, int n4) {
    int i0 = blockIdx.x * blockDim.x + threadIdx.x;
    int stride = gridDim.x * blockDim.x;
    for (int i = i0; i < n4; i += stride) {
        float4 f = ((const float4*)src)[i];
        ushort4 o;
        o.x = f32_to_bf16(f.x); o.y = f32_to_bf16(f.y);
        o.z = f32_to_bf16(f.z); o.w = f32_to_bf16(f.w);
        ((ushort4*)dst)[i] = o;
    }
}

__device__ __forceinline__ void gload16(const void* g, void* l) {
    __builtin_amdgcn_global_load_lds((GAS void*)g, (LAS void*)l, 16, 0, 0);
}

// ---------------- B^T-form GEMM mainloop ----------------
// C[128x128] at (row0,col0) = A[row0..+128, K] * B[col0..+128, K]^T
// A,B row-major with leading dims lda/ldb (elements), K contiguous. bf16 in, f32 acc.
// m97 structure: 128^2 tile, BK=32, 4 waves (2x2), 4x4 16x16x32 frags/wave,
// global_load_lds width-16 staging, 2 barriers per K-step.
__device__ __forceinline__ void gemm_bt_loop(const unsigned short* __restrict__ A, int lda,
                                             const unsigned short* __restrict__ B, int ldb,
                                             int row0, int col0, int ktiles,
                                             unsigned short* lA, unsigned short* lB,
                                             f32x4 acc[4][4]) {
    const int tid  = threadIdx.x;
    const int wave = tid >> 6;
    const int lane = tid & 63;
    const int wr = wave >> 1, wc = wave & 1;
    // staging: issue r covers rows r*64..r*64+63; lane l -> row wave*16 + l/4, col (l%4)*8
    const int srow  = wave * 16 + (lane >> 2);
    const int scol  = (lane & 3) * 8;
    const int lbase = wave * 512;          // LDS elem offset (wave-uniform); +2048 for issue 1
    // fragment read: lane l -> row (l&15) of 16-row frag, k-offset (l>>4)*8
    const int fr = lane & 15;
    const int fk = (lane >> 4) * 8;

    #pragma unroll
    for (int m = 0; m < 4; ++m)
        #pragma unroll
        for (int n = 0; n < 4; ++n)
            #pragma unroll
            for (int q = 0; q < 4; ++q)
                acc[m][n][q] = 0.0f;

    const unsigned short* Arow = A + (size_t)row0 * lda;
    const unsigned short* Brow = B + (size_t)col0 * ldb;

    for (int kt = 0; kt < ktiles; ++kt) {
        const unsigned short* Ag = Arow + (size_t)kt * 32;
        const unsigned short* Bg = Brow + (size_t)kt * 32;
        gload16(Ag + (size_t)srow * lda + scol,        lA + lbase);
        gload16(Ag + (size_t)(srow + 64) * lda + scol, lA + lbase + 2048);
        gload16(Bg + (size_t)srow * ldb + scol,        lB + lbase);
        gload16(Bg + (size_t)(srow + 64) * ldb + scol, lB + lbase + 2048);
        __syncthreads();   // drains vmcnt, tiles visible
        bf16x8 af[4], bfr[4];
        #pragma unroll
        for (int m = 0; m < 4; ++m)
            af[m] = *(const bf16x8*)&lA[(wr*64 + m*16 + fr) * 32 + fk];
        #pragma unroll
        for (int n = 0; n < 4; ++n)
            bfr[n] = *(const bf16x8*)&lB[(wc*64 + n*16 + fr) * 32 + fk];
        #pragma unroll
        for (int m = 0; m < 4; ++m)
            #pragma unroll
            for (int n = 0; n < 4; ++n)
                acc[m][n] = __builtin_amdgcn_mfma_f32_16x16x32_bf16(af[m], bfr[n], acc[m][n], 0, 0, 0);
        __syncthreads();   // before next-tile staging overwrites LDS
    }
}

// ---------------- K1: fused QKV projection + RoPE-sigmoid epilogue ----------------
__global__ __launch_bounds__(256) void k1_proj(const unsigned short* __restrict__ xb,
                                               const unsigned short* __restrict__ Wb,
                                               unsigned short* __restrict__ qkv) {
    __shared__ __align__(16) unsigned short lA[4096];
    __shared__ __align__(16) unsigned short lB[4096];
    const int bi = blockIdx.y, bj = blockIdx.x;
    f32x4 acc[4][4];
    gemm_bt_loop(xb, Ddim, Wb, Ddim, bi*128, bj*128, Ddim/32, lA, lB, acc);
    const int lane = threadIdx.x & 63, wave = threadIdx.x >> 6;
    const int wr = wave >> 1, wc = wave & 1;
    const int er = (lane >> 4) * 4, ec = lane & 15;
    #pragma unroll
    for (int n = 0; n < 4; ++n) {
        const int c = bj*128 + wc*64 + n*16 + ec;
        const bool isQK = (c < 2*Ddim);
        const int ihalf = (c & (Ddim-1)) >> 1;
        float theta = 0.0f;
        if (isQK && ihalf < 2) theta = powf(10000.0f, -2.0f*(float)ihalf);
        #pragma unroll
        for (int m = 0; m < 4; ++m) {
            #pragma unroll
            for (int jj = 0; jj < 4; ++jj) {
                const int t = bi*128 + wr*64 + m*16 + er + jj;
                float v = acc[m][n][jj];
                float ov;
                if (isQK) {
                    float cs = 1.0f;  // exact for ihalf>=2: ang<=4e-13, cos+sin rounds to 1.0f
                    if (ihalf < 2) { float ang = (float)t * theta; cs = cosf(ang) + sinf(ang); }
                    float z = v * cs * (1.0f/2048.0f);
                    ov = 1.0f / (1.0f + expf(-z));
                } else {
                    ov = v;
                }
                qkv[(size_t)t * N1 + c] = f32_to_bf16(ov);
            }
        }
    }
}

// ---------------- K1b: transpose V (qkv cols 4096..6143) -> vT [2048][4096] ----------------
__global__ __launch_bounds__(256) void k1b_trans(const unsigned short* __restrict__ qkv,
                                                 unsigned short* __restrict__ vT) {
    __shared__ unsigned short tile[64][65];
    const int tc = blockIdx.x, tr = blockIdx.y;
    const int x = threadIdx.x & 63, y0 = threadIdx.x >> 6;
    #pragma unroll
    for (int r = 0; r < 64; r += 4) {
        const int row = r + y0;
        tile[row][x] = qkv[(size_t)(tr*64 + row) * N1 + 2*Ddim + tc*64 + x];
    }
    __syncthreads();
    #pragma unroll
    for (int r = 0; r < 64; r += 4) {
        const int row = r + y0;
        vT[(size_t)(tc*64 + row) * Tdim + tr*64 + x] = tile[x][row];
    }
}

// ---------------- K2: A = query @ key^T, causal-masked, lower-tri blocks only ----------------
__global__ __launch_bounds__(256) void k2_qk(const unsigned short* __restrict__ qkv,
                                             unsigned short* __restrict__ Am) {
    __shared__ __align__(16) unsigned short lA[4096];
    __shared__ __align__(16) unsigned short lB[4096];
    const int p = blockIdx.x;
    int bi = (int)((sqrtf(8.0f*(float)p + 1.0f) - 1.0f) * 0.5f);
    while ((bi+1)*(bi+2)/2 <= p) ++bi;
    while (bi*(bi+1)/2 > p) --bi;
    const int bj = p - bi*(bi+1)/2;
    f32x4 acc[4][4];
    gemm_bt_loop(qkv, N1, qkv + Ddim, N1, bi*128, bj*128, Ddim/32, lA, lB, acc);
    const int lane = threadIdx.x & 63, wave = threadIdx.x >> 6;
    const int wr = wave >> 1, wc = wave & 1;
    const int er = (lane >> 4) * 4, ec = lane & 15;
    #pragma unroll
    for (int n = 0; n < 4; ++n) {
        const int s = bj*128 + wc*64 + n*16 + ec;
        #pragma unroll
        for (int m = 0; m < 4; ++m)
            #pragma unroll
            for (int jj = 0; jj < 4; ++jj) {
                const int t = bi*128 + wr*64 + m*16 + er + jj;
                float v = (s <= t) ? acc[m][n][jj] : 0.0f;
                Am[(size_t)t * Tdim + s] = f32_to_bf16(v);
            }
    }
}

// ---------------- K2b: rden[t] = 1 / sum_{s<=t} A[t][s] (deterministic tree) ----------------
__global__ __launch_bounds__(256) void k2b_den(const unsigned short* __restrict__ Am,
                                               float* __restrict__ rden) {
    const int t = blockIdx.x;
    const int lim = ((t >> 7) + 1) << 7;   // diag block is zero-masked above the diagonal
    const unsigned short* row = Am + (size_t)t * Tdim;
    float s = 0.0f;
    for (int idx = threadIdx.x * 8; idx < lim; idx += 2048) {
        uint4 u = *(const uint4*)(row + idx);
        s += bflo(u.x) + bfhi(u.x) + bflo(u.y) + bfhi(u.y)
           + bflo(u.z) + bfhi(u.z) + bflo(u.w) + bfhi(u.w);
    }
    #pragma unroll
    for (int off = 32; off > 0; off >>= 1) s += __shfl_down(s, off, 64);
    __shared__ float red[4];
    const int lane = threadIdx.x & 63, wave = threadIdx.x >> 6;
    if (lane == 0) red[wave] = s;
    __syncthreads();
    if (threadIdx.x == 0) rden[t] = 1.0f / (red[0] + red[1] + red[2] + red[3]);
}

// ---------------- K3: Y = (A @ V) * rden, ragged K capped at diagonal ----------------
__global__ __launch_bounds__(256) void k3_out(const unsigned short* __restrict__ Am,
                                              const unsigned short* __restrict__ vT,
                                              const float* __restrict__ rden,
                                              float* __restrict__ out) {
    __shared__ __align__(16) unsigned short lA[4096];
    __shared__ __align__(16) unsigned short lB[4096];
    const int bi = blockIdx.y, bj = blockIdx.x;
    f32x4 acc[4][4];
    gemm_bt_loop(Am, Tdim, vT, Tdim, bi*128, bj*128, (bi + 1) * 4, lA, lB, acc);
    const int lane = threadIdx.x & 63, wave = threadIdx.x >> 6;
    const int wr = wave >> 1, wc = wave & 1;
    const int er = (lane >> 4) * 4, ec = lane & 15;
    #pragma unroll
    for (int n = 0; n < 4; ++n) {
        const int c = bj*128 + wc*64 + n*16 + ec;
        #pragma unroll
        for (int m = 0; m < 4; ++m)
            #pragma unroll
            for (int jj = 0; jj < 4; ++jj) {
                const int t = bi*128 + wr*64 + m*16 + er + jj;
                out[(size_t)t * Ddim + c] = acc[m][n][jj] * rden[t];
            }
    }
}

// ---------------- launch ----------------
// Workspace layout (bytes):
//   [0,        16777216)  xb   (bf16 x)          -- dead after K1, reused by Am
//   [16777216, 41943040)  Wb   (bf16 Wq|Wk|Wv)   -- dead after K1, reused by Am
//   [0,        33554432)  Am   (bf16 A, aliases xb+Wb)
//   [41943040, 92274688)  qkv  (bf16 [4096][6144])
//   [92274688,109051904)  vT   (bf16 [2048][4096])
//   [109051904,109068288) rden (f32 [4096])
// Total required: ~104 MB.
extern "C" void kernel_launch(void* const* d_in, const int* in_sizes, int n_in,
                              void* d_out, int out_size, void* d_ws, size_t ws_size,
                              hipStream_t stream) {
    const float* x  = (const float*)d_in[0];
    const float* Wq = (const float*)d_in[1];
    const float* Wk = (const float*)d_in[2];
    const float* Wv = (const float*)d_in[3];
    char* ws = (char*)d_ws;
    unsigned short* xb   = (unsigned short*)(ws + 0);
    unsigned short* Wb   = (unsigned short*)(ws + (size_t)16777216);
    unsigned short* qkv  = (unsigned short*)(ws + (size_t)41943040);
    unsigned short* vT   = (unsigned short*)(ws + (size_t)92274688);
    unsigned short* Am   = (unsigned short*)(ws + 0);   // aliases xb/Wb (both dead by K2)
    float*          rden = (float*)(ws + (size_t)109051904);
    float* out = (float*)d_out;

    cvt_bf16<<<2048, 256, 0, stream>>>(x,  xb, (Tdim*Ddim)/4);
    cvt_bf16<<<1024, 256, 0, stream>>>(Wq, Wb,                  (Ddim*Ddim)/4);
    cvt_bf16<<<1024, 256, 0, stream>>>(Wk, Wb + Ddim*Ddim,      (Ddim*Ddim)/4);
    cvt_bf16<<<1024, 256, 0, stream>>>(Wv, Wb + 2*Ddim*Ddim,    (Ddim*Ddim)/4);
    k1_proj <<<dim3(N1/128, Tdim/128), 256, 0, stream>>>(xb, Wb, qkv);
    k1b_trans<<<dim3(Ddim/64, Tdim/64), 256, 0, stream>>>(qkv, vT);
    k2_qk   <<<dim3(528), 256, 0, stream>>>(qkv, Am);
    k2b_den <<<dim3(Tdim), 256, 0, stream>>>(Am, rden);
    k3_out  <<<dim3(Ddim/128, Tdim/128), 256, 0, stream>>>(Am, vT, rden, out);
}

// Round 2
// 280.675 us; speedup vs baseline: 1.3596x; 1.3596x over previous
//
#include <hip/hip_runtime.h>
#include <hip/hip_bf16.h>
#include <cstdint>
#include <cstddef>

using bf16x8 = __attribute__((ext_vector_type(8))) short;
using f32x4  = __attribute__((ext_vector_type(4))) float;

#define GAS __attribute__((address_space(1)))
#define LAS __attribute__((address_space(3)))

static constexpr int Tdim = 4096;
static constexpr int Ddim = 2048;
static constexpr int N1   = 6144;   // 3*Ddim

// --- deep-pipeline GEMM geometry: 128x256 tile, BK=32, 8 waves (2M x 4N) ---
static constexpr int BM   = 128;
static constexpr int BN   = 256;
static constexpr int BUFB = (BM + BN) * 64;   // 24576 B per K-tile buffer (A | B)
static constexpr int NBUF = 4;                // ring depth (stage 3 ahead)
static constexpr int LDSB = NBUF * BUFB;      // 98304 B

__device__ __forceinline__ unsigned short f32_to_bf16(float f) {
    union { float f; unsigned u; } v; v.f = f;
    return (unsigned short)((v.u + 0x7FFFu + ((v.u >> 16) & 1u)) >> 16);
}
__device__ __forceinline__ float bflo(unsigned u){ union{unsigned x;float f;}v; v.x = u << 16;        return v.f; }
__device__ __forceinline__ float bfhi(unsigned u){ union{unsigned x;float f;}v; v.x = u & 0xFFFF0000u; return v.f; }

__global__ __launch_bounds__(256) void cvt_bf16(const float* __restrict__ src,
                                                unsigned short* __restrict__ dst, int n4) {
    int i0 = blockIdx.x * blockDim.x + threadIdx.x;
    int stride = gridDim.x * blockDim.x;
    for (int i = i0; i < n4; i += stride) {
        float4 f = ((const float4*)src)[i];
        ushort4 o;
        o.x = f32_to_bf16(f.x); o.y = f32_to_bf16(f.y);
        o.z = f32_to_bf16(f.z); o.w = f32_to_bf16(f.w);
        ((ushort4*)dst)[i] = o;
    }
}

__device__ __forceinline__ void gload16(const void* g, void* l) {
    __builtin_amdgcn_global_load_lds((GAS void*)g, (LAS void*)l, 16, 0, 0);
}

// T2 swizzle: LDS[r][c'] = G[r][c' ^ swz(r)], involution on byte bits [5:4].
// Row stride 64B -> bank period 2 rows (8-way conflict); XOR with (r>>1)&3
// spreads 16 consecutive rows over all 8 16B slots -> conflict-free ds_read_b128.
__device__ __forceinline__ int swz(int r) { return ((r >> 1) & 3) << 4; }

// C = A[row0..+128, K] * B[col0..+256, K]^T ; A,B row-major bf16, K contiguous.
// Counted-vmcnt 4-deep ring: stage tile t+3 while computing tile t; vmcnt(6)
// steady (2 tiles x 3 loads in flight across the barrier), 3/0 at the tail.
__device__ __forceinline__ void pipe_gemm(const unsigned short* __restrict__ Ag, int lda,
                                          const unsigned short* __restrict__ Bg, int ldb,
                                          int row0, int col0, int nt,
                                          char* lds, f32x4 acc[4][4]) {
    const int tid = threadIdx.x, wave = tid >> 6, lane = tid & 63;
    const int wr = wave >> 2, wc = wave & 3;           // 2M x 4N wave grid

    // staging descriptors: 3 issues x 8KB cover A(8KB) + B(16KB) per K-tile.
    // LDS linear offset o -> (region, r, c'); global src pre-swizzled (rule 21).
    const char* gp[3]; int lo[3];
    #pragma unroll
    for (int i = 0; i < 3; ++i) {
        int o = i * 8192 + wave * 1024 + (lane << 4);
        lo[i] = i * 8192 + wave * 1024;                // wave-uniform LDS base
        if (o < BM * 64) {
            int r = o >> 6, cp = o & 63;
            gp[i] = (const char*)Ag + (size_t)(row0 + r) * (size_t)(lda * 2) + (cp ^ swz(r));
        } else {
            int o2 = o - BM * 64; int r = o2 >> 6, cp = o2 & 63;
            gp[i] = (const char*)Bg + (size_t)(col0 + r) * (size_t)(ldb * 2) + (cp ^ swz(r));
        }
    }
    // fragment read offsets (swizzled): lane -> row (lane&15), 16B k-slot (lane>>4)
    const int fr = lane & 15, fkB = (lane >> 4) << 4;
    int offA[4], offB[4];
    #pragma unroll
    for (int m = 0; m < 4; ++m) { int r = wr*64 + m*16 + fr; offA[m] = r*64 + (fkB ^ swz(r)); }
    #pragma unroll
    for (int n = 0; n < 4; ++n) { int r = wc*64 + n*16 + fr; offB[n] = BM*64 + r*64 + (fkB ^ swz(r)); }

    #pragma unroll
    for (int m = 0; m < 4; ++m)
        #pragma unroll
        for (int n = 0; n < 4; ++n)
            #pragma unroll
            for (int q = 0; q < 4; ++q) acc[m][n][q] = 0.0f;

    // prologue: stage tiles 0..2, wait for tile 0 (leave 6 in flight)
    for (int tt = 0; tt < 3; ++tt) {
        char* dst = lds + tt * BUFB;
        #pragma unroll
        for (int i = 0; i < 3; ++i) gload16(gp[i] + (size_t)tt * 64, dst + lo[i]);
    }
    asm volatile("s_waitcnt vmcnt(6)" ::: "memory");
    __builtin_amdgcn_s_barrier();
    __builtin_amdgcn_sched_barrier(0);

    for (int t = 0; t < nt; ++t) {
        const char* buf = lds + (t & 3) * BUFB;
        bf16x8 af[4], bq[4];
        #pragma unroll
        for (int m = 0; m < 4; ++m) af[m] = *(const bf16x8*)(buf + offA[m]);
        #pragma unroll
        for (int n = 0; n < 4; ++n) bq[n] = *(const bf16x8*)(buf + offB[n]);
        if (t + 3 < nt) {                              // stage tile t+3 into buf[(t-1)&3]
            char* dst = lds + ((t + 3) & 3) * BUFB;    // safe: all waves done reading it
            const size_t ko = (size_t)(t + 3) * 64;    // (barrier at end of iter t-1)
            #pragma unroll
            for (int i = 0; i < 3; ++i) gload16(gp[i] + ko, dst + lo[i]);
        }
        __builtin_amdgcn_s_setprio(1);
        #pragma unroll
        for (int m = 0; m < 4; ++m)
            #pragma unroll
            for (int n = 0; n < 4; ++n)
                acc[m][n] = __builtin_amdgcn_mfma_f32_16x16x32_bf16(af[m], bq[n], acc[m][n], 0, 0, 0);
        __builtin_amdgcn_s_setprio(0);
        __builtin_amdgcn_sched_barrier(0);             // pin MFMAs (and their ds_reads) here
        if (t + 1 < nt) {
            if (t + 4 <= nt)      asm volatile("s_waitcnt vmcnt(6)" ::: "memory"); // tile t+1 landed
            else if (t + 3 == nt) asm volatile("s_waitcnt vmcnt(3)" ::: "memory");
            else                  asm volatile("s_waitcnt vmcnt(0)" ::: "memory");
            __builtin_amdgcn_s_barrier();
            __builtin_amdgcn_sched_barrier(0);
            asm volatile("" ::: "memory");
        }
    }
}

// ---------------- K1: fused QKV projection + sigmoid epilogue ----------------
__global__ __launch_bounds__(512, 2) void k1_proj(const unsigned short* __restrict__ xb,
                                                  const unsigned short* __restrict__ Wb,
                                                  unsigned short* __restrict__ qkv) {
    extern __shared__ __align__(16) char lds[];
    const int bi = blockIdx.y, bj = blockIdx.x;
    f32x4 acc[4][4];
    pipe_gemm(xb, Ddim, Wb, Ddim, bi*BM, bj*BN, Ddim/32, lds, acc);
    const int lane = threadIdx.x & 63, wave = threadIdx.x >> 6;
    const int wr = wave >> 2, wc = wave & 3;
    const int er = (lane >> 4) * 4, ec = lane & 15;
    #pragma unroll
    for (int n = 0; n < 4; ++n) {
        const int c = bj*BN + wc*64 + n*16 + ec;
        const bool isQK = (c < 2*Ddim);
        const int ihalf = (c & (Ddim-1)) >> 1;
        float theta = 0.0f;
        if (isQK && ihalf < 2) theta = powf(10000.0f, -2.0f*(float)ihalf);
        #pragma unroll
        for (int m = 0; m < 4; ++m) {
            #pragma unroll
            for (int jj = 0; jj < 4; ++jj) {
                const int t = bi*BM + wr*64 + m*16 + er + jj;
                float v = acc[m][n][jj];
                float ov;
                if (isQK) {
                    float cs = 1.0f;  // exact for ihalf>=2 (ang<=4e-13 -> cos+sin==1.0f)
                    if (ihalf < 2) { float ang = (float)t * theta; cs = cosf(ang) + sinf(ang); }
                    float z = v * cs * (1.0f/2048.0f);
                    ov = 1.0f / (1.0f + expf(-z));
                } else {
                    ov = v;
                }
                qkv[(size_t)t * N1 + c] = f32_to_bf16(ov);
            }
        }
    }
}

// ---------------- K1b: transpose V -> vT [2048][4096] ----------------
__global__ __launch_bounds__(256) void k1b_trans(const unsigned short* __restrict__ qkv,
                                                 unsigned short* __restrict__ vT) {
    __shared__ unsigned short tile[64][65];
    const int tc = blockIdx.x, tr = blockIdx.y;
    const int x = threadIdx.x & 63, y0 = threadIdx.x >> 6;
    #pragma unroll
    for (int r = 0; r < 64; r += 4) {
        const int row = r + y0;
        tile[row][x] = qkv[(size_t)(tr*64 + row) * N1 + 2*Ddim + tc*64 + x];
    }
    __syncthreads();
    #pragma unroll
    for (int r = 0; r < 64; r += 4) {
        const int row = r + y0;
        vT[(size_t)(tc*64 + row) * Tdim + tr*64 + x] = tile[x][row];
    }
}

// ---------------- K2: A = query @ key^T, lower-tri 128x256 blocks ----------------
__global__ __launch_bounds__(512, 2) void k2_qk(const unsigned short* __restrict__ qkv,
                                                unsigned short* __restrict__ Am) {
    extern __shared__ __align__(16) char lds[];
    // enumerate blocks (bi rows of 128, bj cols of 256) with bj <= bi/2: 272 total
    int p = blockIdx.x, bi = 0, c0 = 0;
    while (c0 + (bi >> 1) + 1 <= p) { c0 += (bi >> 1) + 1; ++bi; }
    const int bj = p - c0;
    f32x4 acc[4][4];
    pipe_gemm(qkv, N1, qkv + Ddim, N1, bi*BM, bj*BN, Ddim/32, lds, acc);
    const int lane = threadIdx.x & 63, wave = threadIdx.x >> 6;
    const int wr = wave >> 2, wc = wave & 3;
    const int er = (lane >> 4) * 4, ec = lane & 15;
    #pragma unroll
    for (int n = 0; n < 4; ++n) {
        const int s = bj*BN + wc*64 + n*16 + ec;
        #pragma unroll
        for (int m = 0; m < 4; ++m)
            #pragma unroll
            for (int jj = 0; jj < 4; ++jj) {
                const int t = bi*BM + wr*64 + m*16 + er + jj;
                float v = (s <= t) ? acc[m][n][jj] : 0.0f;
                Am[(size_t)t * Tdim + s] = f32_to_bf16(v);
            }
    }
}

// ---------------- K2b: rden[t] = 1 / sum_{s<=t} A[t][s] ----------------
__global__ __launch_bounds__(256) void k2b_den(const unsigned short* __restrict__ Am,
                                               float* __restrict__ rden) {
    const int t = blockIdx.x;
    const int lim = ((t >> 7) + 1) << 7;   // zeros above diagonal inside written tiles
    const unsigned short* row = Am + (size_t)t * Tdim;
    float s = 0.0f;
    for (int idx = threadIdx.x * 8; idx < lim; idx += 2048) {
        uint4 u = *(const uint4*)(row + idx);
        s += bflo(u.x) + bfhi(u.x) + bflo(u.y) + bfhi(u.y)
           + bflo(u.z) + bfhi(u.z) + bflo(u.w) + bfhi(u.w);
    }
    #pragma unroll
    for (int off = 32; off > 0; off >>= 1) s += __shfl_down(s, off, 64);
    __shared__ float red[4];
    const int lane = threadIdx.x & 63, wave = threadIdx.x >> 6;
    if (lane == 0) red[wave] = s;
    __syncthreads();
    if (threadIdx.x == 0) rden[t] = 1.0f / (red[0] + red[1] + red[2] + red[3]);
}

// ---------------- K3: Y = (A @ V) * rden, ragged K capped at diagonal ----------------
__global__ __launch_bounds__(512, 2) void k3_out(const unsigned short* __restrict__ Am,
                                                 const unsigned short* __restrict__ vT,
                                                 const float* __restrict__ rden,
                                                 float* __restrict__ out) {
    extern __shared__ __align__(16) char lds[];
    const int bi = blockIdx.y, bj = blockIdx.x;
    f32x4 acc[4][4];
    pipe_gemm(Am, Tdim, vT, Tdim, bi*BM, bj*BN, (bi + 1) * 4, lds, acc);
    const int lane = threadIdx.x & 63, wave = threadIdx.x >> 6;
    const int wr = wave >> 2, wc = wave & 3;
    const int er = (lane >> 4) * 4, ec = lane & 15;
    #pragma unroll
    for (int n = 0; n < 4; ++n) {
        const int c = bj*BN + wc*64 + n*16 + ec;
        #pragma unroll
        for (int m = 0; m < 4; ++m)
            #pragma unroll
            for (int jj = 0; jj < 4; ++jj) {
                const int t = bi*BM + wr*64 + m*16 + er + jj;
                out[(size_t)t * Ddim + c] = acc[m][n][jj] * rden[t];
            }
    }
}

// ---------------- launch ----------------
// Workspace layout (bytes):
//   [0,        33554432)  xb+Wb (dead after K1) -> reused as Am (bf16 4096x4096)
//   [41943040, 92274688)  qkv  (bf16 [4096][6144])
//   [92274688,109051904)  vT   (bf16 [2048][4096])
//   [109051904,109068288) rden (f32 [4096])
extern "C" void kernel_launch(void* const* d_in, const int* in_sizes, int n_in,
                              void* d_out, int out_size, void* d_ws, size_t ws_size,
                              hipStream_t stream) {
    const float* x  = (const float*)d_in[0];
    const float* Wq = (const float*)d_in[1];
    const float* Wk = (const float*)d_in[2];
    const float* Wv = (const float*)d_in[3];
    char* ws = (char*)d_ws;
    unsigned short* xb   = (unsigned short*)(ws + 0);
    unsigned short* Wb   = (unsigned short*)(ws + (size_t)16777216);
    unsigned short* qkv  = (unsigned short*)(ws + (size_t)41943040);
    unsigned short* vT   = (unsigned short*)(ws + (size_t)92274688);
    unsigned short* Am   = (unsigned short*)(ws + 0);
    float*          rden = (float*)(ws + (size_t)109051904);
    float* out = (float*)d_out;

    // allow 96KB dynamic LDS (no-op if already permitted); not a stream op
    (void)hipFuncSetAttribute((const void*)k1_proj, hipFuncAttributeMaxDynamicSharedMemorySize, LDSB);
    (void)hipFuncSetAttribute((const void*)k2_qk,   hipFuncAttributeMaxDynamicSharedMemorySize, LDSB);
    (void)hipFuncSetAttribute((const void*)k3_out,  hipFuncAttributeMaxDynamicSharedMemorySize, LDSB);

    cvt_bf16<<<2048, 256, 0, stream>>>(x,  xb, (Tdim*Ddim)/4);
    cvt_bf16<<<1024, 256, 0, stream>>>(Wq, Wb,                  (Ddim*Ddim)/4);
    cvt_bf16<<<1024, 256, 0, stream>>>(Wk, Wb + Ddim*Ddim,      (Ddim*Ddim)/4);
    cvt_bf16<<<1024, 256, 0, stream>>>(Wv, Wb + 2*Ddim*Ddim,    (Ddim*Ddim)/4);
    k1_proj <<<dim3(N1/BN, Tdim/BM), 512, LDSB, stream>>>(xb, Wb, qkv);
    k1b_trans<<<dim3(Ddim/64, Tdim/64), 256, 0, stream>>>(qkv, vT);
    k2_qk   <<<dim3(272), 512, LDSB, stream>>>(qkv, Am);
    k2b_den <<<dim3(Tdim), 256, 0, stream>>>(Am, rden);
    k3_out  <<<dim3(Ddim/BN, Tdim/BM), 512, LDSB, stream>>>(Am, vT, rden, out);
}

// Round 3
// 263.520 us; speedup vs baseline: 1.4481x; 1.0651x over previous
//
#include <hip/hip_runtime.h>
#include <hip/hip_bf16.h>
#include <cstdint>
#include <cstddef>

using bf16x8 = __attribute__((ext_vector_type(8))) short;
using f32x4  = __attribute__((ext_vector_type(4))) float;

#define GAS __attribute__((address_space(1)))
#define LAS __attribute__((address_space(3)))

static constexpr int Tdim = 4096;
static constexpr int Ddim = 2048;
static constexpr int N1   = 6144;   // 3*Ddim

__device__ __forceinline__ unsigned short f32_to_bf16(float f) {
    union { float f; unsigned u; } v; v.f = f;
    return (unsigned short)((v.u + 0x7FFFu + ((v.u >> 16) & 1u)) >> 16);
}
__device__ __forceinline__ float bflo(unsigned u){ union{unsigned x;float f;}v; v.x = u << 16;        return v.f; }
__device__ __forceinline__ float bfhi(unsigned u){ union{unsigned x;float f;}v; v.x = u & 0xFFFF0000u; return v.f; }

// ---------------- fused f32 -> bf16 conversion for x, Wq, Wk, Wv ----------------
__global__ __launch_bounds__(256) void cvt_all(const float* __restrict__ x,
                                               const float* __restrict__ Wq,
                                               const float* __restrict__ Wk,
                                               const float* __restrict__ Wv,
                                               unsigned short* __restrict__ xb,
                                               unsigned short* __restrict__ Wb) {
    constexpr int NX = (Tdim * Ddim) / 4;      // float4 units
    constexpr int NWm = (Ddim * Ddim) / 4;
    const int i0 = blockIdx.x * blockDim.x + threadIdx.x;
    const int stride = gridDim.x * blockDim.x;
    for (int i = i0; i < NX + 3 * NWm; i += stride) {
        const float* s; unsigned short* d; int j;
        if (i < NX)            { s = x;  d = xb;                            j = i; }
        else if (i < NX+NWm)   { s = Wq; d = Wb;                            j = i - NX; }
        else if (i < NX+2*NWm) { s = Wk; d = Wb + (size_t)Ddim*Ddim;        j = i - NX - NWm; }
        else                   { s = Wv; d = Wb + 2*(size_t)Ddim*Ddim;      j = i - NX - 2*NWm; }
        float4 f = ((const float4*)s)[j];
        ushort4 o;
        o.x = f32_to_bf16(f.x); o.y = f32_to_bf16(f.y);
        o.z = f32_to_bf16(f.z); o.w = f32_to_bf16(f.w);
        ((ushort4*)d)[j] = o;
    }
}

__device__ __forceinline__ void gload16(const void* g, void* l) {
    __builtin_amdgcn_global_load_lds((GAS void*)g, (LAS void*)l, 16, 0, 0);
}

// T2 swizzle (involution on byte bits [5:4]): spreads 16 consecutive rows of a
// 64B-stride tile across all 8 16B slots -> conflict-free ds_read_b128 (verified: 0 conflicts).
__device__ __forceinline__ int swz(int r) { return ((r >> 1) & 3) << 4; }

// C[128 x TBN] = A[row0..+128, K] * B[col0..+TBN, K]^T ; bf16 row-major, K contiguous.
// 3-deep LDS ring, stage-ahead-2, counted vmcnt (never 0 mid-loop).
// NW waves in a 2 x (NW/2) grid, per-wave 64x64 output (4x4 16x16x32 frags).
template<int TBN, int NW>
__device__ __forceinline__ void pipe_gemm(const unsigned short* __restrict__ Ag, int lda,
                                          const unsigned short* __restrict__ Bg, int ldb,
                                          int row0, int col0, int nt,
                                          char* lds, f32x4 acc[4][4]) {
    constexpr int WCOL   = NW / 2;
    constexpr int ISSUES = (128 + TBN) / (NW * 16);  // gload16 per wave per K-tile
    constexpr int BUF    = (128 + TBN) * 64;         // bytes per K-tile buffer (A|B)
    const int tid = threadIdx.x, wave = tid >> 6, lane = tid & 63;
    const int wr = wave / WCOL, wc = wave % WCOL;

    // staging descriptors: LDS linear (DMA constraint), global src pre-swizzled (rule 21)
    const char* gp[ISSUES]; int lo[ISSUES];
    #pragma unroll
    for (int i = 0; i < ISSUES; ++i) {
        int o = i * (NW * 1024) + wave * 1024 + (lane << 4);
        lo[i] = i * (NW * 1024) + wave * 1024;       // wave-uniform LDS base
        if (o < 128 * 64) {
            int r = o >> 6, cp = o & 63;
            gp[i] = (const char*)Ag + (size_t)(row0 + r) * (size_t)lda * 2 + (cp ^ swz(r));
        } else {
            int o2 = o - 128 * 64; int r = o2 >> 6, cp = o2 & 63;
            gp[i] = (const char*)Bg + (size_t)(col0 + r) * (size_t)ldb * 2 + (cp ^ swz(r));
        }
    }
    // fragment read offsets (swizzled)
    const int fr = lane & 15, fkB = (lane >> 4) << 4;
    int offA[4], offB[4];
    #pragma unroll
    for (int m = 0; m < 4; ++m) { int r = wr*64 + m*16 + fr; offA[m] = r*64 + (fkB ^ swz(r)); }
    #pragma unroll
    for (int n = 0; n < 4; ++n) { int r = wc*64 + n*16 + fr; offB[n] = 128*64 + r*64 + (fkB ^ swz(r)); }

    #pragma unroll
    for (int m = 0; m < 4; ++m)
        #pragma unroll
        for (int n = 0; n < 4; ++n)
            #pragma unroll
            for (int q = 0; q < 4; ++q) acc[m][n][q] = 0.0f;

    // prologue: stage tiles 0,1; wait tile 0 (leave tile 1's loads in flight)
    #pragma unroll
    for (int tt = 0; tt < 2; ++tt) {
        char* dst = lds + tt * BUF;
        #pragma unroll
        for (int i = 0; i < ISSUES; ++i) gload16(gp[i] + (size_t)tt * 64, dst + lo[i]);
    }
    asm volatile("s_waitcnt vmcnt(%0)" :: "n"(ISSUES) : "memory");
    __builtin_amdgcn_s_barrier();
    __builtin_amdgcn_sched_barrier(0);

    int cur = 0, stg = 2 * BUF;                      // buffers: t%3, stage target (t+2)%3
    for (int t = 0; t < nt; ++t) {
        const char* buf = lds + cur;
        bf16x8 af[4], bq[4];
        #pragma unroll
        for (int m = 0; m < 4; ++m) af[m] = *(const bf16x8*)(buf + offA[m]);
        #pragma unroll
        for (int n = 0; n < 4; ++n) bq[n] = *(const bf16x8*)(buf + offB[n]);
        if (t + 2 < nt) {                            // stage tile t+2 (buffer read at t-1: safe)
            char* dst = lds + stg;
            const size_t ko = (size_t)(t + 2) * 64;
            #pragma unroll
            for (int i = 0; i < ISSUES; ++i) gload16(gp[i] + ko, dst + lo[i]);
        }
        __builtin_amdgcn_s_setprio(1);
        #pragma unroll
        for (int m = 0; m < 4; ++m)
            #pragma unroll
            for (int n = 0; n < 4; ++n)
                acc[m][n] = __builtin_amdgcn_mfma_f32_16x16x32_bf16(af[m], bq[n], acc[m][n], 0, 0, 0);
        __builtin_amdgcn_s_setprio(0);
        __builtin_amdgcn_sched_barrier(0);
        if (t + 1 < nt) {
            if (t + 3 <= nt) asm volatile("s_waitcnt vmcnt(%0)" :: "n"(ISSUES) : "memory");
            else             asm volatile("s_waitcnt vmcnt(0)" ::: "memory");
            __builtin_amdgcn_s_barrier();
            __builtin_amdgcn_sched_barrier(0);
        }
        cur = (cur == 2*BUF) ? 0 : cur + BUF;
        stg = (stg == 2*BUF) ? 0 : stg + BUF;
    }
}

static constexpr int LDS_K1 = 3 * (128 + 256) * 64;  // 73728 B -> 2 blocks/CU
static constexpr int LDS_K2 = 3 * (128 + 128) * 64;  // 49152 B -> 3 blocks/CU

// ---------------- K1: fused QKV projection + sigmoid epilogue (128x256, 8 waves) ----------------
__global__ __launch_bounds__(512, 4) void k1_proj(const unsigned short* __restrict__ xb,
                                                  const unsigned short* __restrict__ Wb,
                                                  unsigned short* __restrict__ qkv) {
    extern __shared__ __align__(16) char lds[];
    const int bi = blockIdx.y, bj = blockIdx.x;
    f32x4 acc[4][4];
    pipe_gemm<256, 8>(xb, Ddim, Wb, Ddim, bi*128, bj*256, Ddim/32, lds, acc);
    const int lane = threadIdx.x & 63, wave = threadIdx.x >> 6;
    const int wr = wave >> 2, wc = wave & 3;
    const int er = (lane >> 4) * 4, ec = lane & 15;
    #pragma unroll
    for (int n = 0; n < 4; ++n) {
        const int c = bj*256 + wc*64 + n*16 + ec;
        const bool isQK = (c < 2*Ddim);
        const int ihalf = (c & (Ddim-1)) >> 1;
        float theta = 0.0f;
        if (isQK && ihalf < 2) theta = powf(10000.0f, -2.0f*(float)ihalf);
        #pragma unroll
        for (int m = 0; m < 4; ++m) {
            #pragma unroll
            for (int jj = 0; jj < 4; ++jj) {
                const int t = bi*128 + wr*64 + m*16 + er + jj;
                float v = acc[m][n][jj];
                float ov;
                if (isQK) {
                    float cs = 1.0f;  // exact for ihalf>=2 (ang<=4e-13 -> cos+sin==1.0f)
                    if (ihalf < 2) { float ang = (float)t * theta; cs = cosf(ang) + sinf(ang); }
                    float z = v * cs * (1.0f/2048.0f);
                    ov = 1.0f / (1.0f + expf(-z));
                } else {
                    ov = v;
                }
                qkv[(size_t)t * N1 + c] = f32_to_bf16(ov);
            }
        }
    }
}

// ---------------- K1b: transpose V -> vT [2048][4096] ----------------
__global__ __launch_bounds__(256) void k1b_trans(const unsigned short* __restrict__ qkv,
                                                 unsigned short* __restrict__ vT) {
    __shared__ unsigned short tile[64][65];
    const int tc = blockIdx.x, tr = blockIdx.y;
    const int x = threadIdx.x & 63, y0 = threadIdx.x >> 6;
    #pragma unroll
    for (int r = 0; r < 64; r += 4) {
        const int row = r + y0;
        tile[row][x] = qkv[(size_t)(tr*64 + row) * N1 + 2*Ddim + tc*64 + x];
    }
    __syncthreads();
    #pragma unroll
    for (int r = 0; r < 64; r += 4) {
        const int row = r + y0;
        vT[(size_t)(tc*64 + row) * Tdim + tr*64 + x] = tile[x][row];
    }
}

// ---------------- K2: A = query @ key^T, lower-tri 128x128 blocks (528) ----------------
__global__ __launch_bounds__(256, 3) void k2_qk(const unsigned short* __restrict__ qkv,
                                                unsigned short* __restrict__ Am) {
    extern __shared__ __align__(16) char lds[];
    const int p = blockIdx.x;
    int bi = (int)((sqrtf(8.0f*(float)p + 1.0f) - 1.0f) * 0.5f);
    while ((bi+1)*(bi+2)/2 <= p) ++bi;
    while (bi*(bi+1)/2 > p) --bi;
    const int bj = p - bi*(bi+1)/2;
    f32x4 acc[4][4];
    pipe_gemm<128, 4>(qkv, N1, qkv + Ddim, N1, bi*128, bj*128, Ddim/32, lds, acc);
    const int lane = threadIdx.x & 63, wave = threadIdx.x >> 6;
    const int wr = wave >> 1, wc = wave & 1;
    const int er = (lane >> 4) * 4, ec = lane & 15;
    #pragma unroll
    for (int n = 0; n < 4; ++n) {
        const int s = bj*128 + wc*64 + n*16 + ec;
        #pragma unroll
        for (int m = 0; m < 4; ++m)
            #pragma unroll
            for (int jj = 0; jj < 4; ++jj) {
                const int t = bi*128 + wr*64 + m*16 + er + jj;
                float v = (s <= t) ? acc[m][n][jj] : 0.0f;
                Am[(size_t)t * Tdim + s] = f32_to_bf16(v);
            }
    }
}

// ---------------- K2b: rden[t] = 1 / sum_{s<=t} A[t][s] ----------------
__global__ __launch_bounds__(256) void k2b_den(const unsigned short* __restrict__ Am,
                                               float* __restrict__ rden) {
    const int t = blockIdx.x;
    const int lim = ((t >> 7) + 1) << 7;
    const unsigned short* row = Am + (size_t)t * Tdim;
    float s = 0.0f;
    for (int idx = threadIdx.x * 8; idx < lim; idx += 2048) {
        uint4 u = *(const uint4*)(row + idx);
        s += bflo(u.x) + bfhi(u.x) + bflo(u.y) + bfhi(u.y)
           + bflo(u.z) + bfhi(u.z) + bflo(u.w) + bfhi(u.w);
    }
    #pragma unroll
    for (int off = 32; off > 0; off >>= 1) s += __shfl_down(s, off, 64);
    __shared__ float red[4];
    const int lane = threadIdx.x & 63, wave = threadIdx.x >> 6;
    if (lane == 0) red[wave] = s;
    __syncthreads();
    if (threadIdx.x == 0) rden[t] = 1.0f / (red[0] + red[1] + red[2] + red[3]);
}

// ---------------- K3: Y = (A @ V) * rden, ragged K, 128x128 blocks ----------------
__global__ __launch_bounds__(256, 3) void k3_out(const unsigned short* __restrict__ Am,
                                                 const unsigned short* __restrict__ vT,
                                                 const float* __restrict__ rden,
                                                 float* __restrict__ out) {
    extern __shared__ __align__(16) char lds[];
    const int bi = blockIdx.y, bj = blockIdx.x;
    f32x4 acc[4][4];
    pipe_gemm<128, 4>(Am, Tdim, vT, Tdim, bi*128, bj*128, (bi + 1) * 4, lds, acc);
    const int lane = threadIdx.x & 63, wave = threadIdx.x >> 6;
    const int wr = wave >> 1, wc = wave & 1;
    const int er = (lane >> 4) * 4, ec = lane & 15;
    #pragma unroll
    for (int n = 0; n < 4; ++n) {
        const int c = bj*128 + wc*64 + n*16 + ec;
        #pragma unroll
        for (int m = 0; m < 4; ++m)
            #pragma unroll
            for (int jj = 0; jj < 4; ++jj) {
                const int t = bi*128 + wr*64 + m*16 + er + jj;
                out[(size_t)t * Ddim + c] = acc[m][n][jj] * rden[t];
            }
    }
}

// ---------------- launch ----------------
// Workspace layout (bytes):
//   [0,        33554432)  xb+Wb (dead after K1) -> reused as Am (bf16 4096x4096)
//   [41943040, 92274688)  qkv  (bf16 [4096][6144])
//   [92274688,109051904)  vT   (bf16 [2048][4096])
//   [109051904,109068288) rden (f32 [4096])
extern "C" void kernel_launch(void* const* d_in, const int* in_sizes, int n_in,
                              void* d_out, int out_size, void* d_ws, size_t ws_size,
                              hipStream_t stream) {
    const float* x  = (const float*)d_in[0];
    const float* Wq = (const float*)d_in[1];
    const float* Wk = (const float*)d_in[2];
    const float* Wv = (const float*)d_in[3];
    char* ws = (char*)d_ws;
    unsigned short* xb   = (unsigned short*)(ws + 0);
    unsigned short* Wb   = (unsigned short*)(ws + (size_t)16777216);
    unsigned short* qkv  = (unsigned short*)(ws + (size_t)41943040);
    unsigned short* vT   = (unsigned short*)(ws + (size_t)92274688);
    unsigned short* Am   = (unsigned short*)(ws + 0);
    float*          rden = (float*)(ws + (size_t)109051904);
    float* out = (float*)d_out;

    (void)hipFuncSetAttribute((const void*)k1_proj, hipFuncAttributeMaxDynamicSharedMemorySize, LDS_K1);

    cvt_all <<<2048, 256, 0, stream>>>(x, Wq, Wk, Wv, xb, Wb);
    k1_proj <<<dim3(N1/256, Tdim/128), 512, LDS_K1, stream>>>(xb, Wb, qkv);
    k1b_trans<<<dim3(Ddim/64, Tdim/64), 256, 0, stream>>>(qkv, vT);
    k2_qk   <<<dim3(528), 256, LDS_K2, stream>>>(qkv, Am);
    k2b_den <<<dim3(Tdim), 256, 0, stream>>>(Am, rden);
    k3_out  <<<dim3(Ddim/128, Tdim/128), 256, LDS_K2, stream>>>(Am, vT, rden, out);
}